// Round 10
// baseline (185.627 us; speedup 1.0000x reference)
//
#include <hip/hip_runtime.h>
#include <hip/hip_bf16.h>
#include <math.h>

typedef __bf16 bf16;
typedef __bf16 bf16x4 __attribute__((ext_vector_type(4)));
typedef __bf16 bf16x8 __attribute__((ext_vector_type(8)));
typedef float f32x2 __attribute__((ext_vector_type(2)));
typedef float f32x4 __attribute__((ext_vector_type(4)));

#define NB 4
#define NN 1024
#define ND 256
#define NH 8
#define INFV 1e38f
#define RTHR2 11.5f          // defer-max threshold, log2 domain (~e^8)
#define LOG2E 1.44269504f
#define ZSPLIT 4

__device__ __forceinline__ f32x4 mfma16(bf16x8 a, bf16x8 b, f32x4 c) {
    return __builtin_amdgcn_mfma_f32_16x16x32_bf16(a, b, c, 0, 0, 0);
}
__device__ __forceinline__ f32x2 sp2(float v) { return f32x2{v, v}; }
__device__ __forceinline__ f32x2 fma2(f32x2 a, float b, f32x2 c) {
    return __builtin_elementwise_fma(a, sp2(b), c);
}
__device__ __forceinline__ unsigned cvtpk(float lo, float hi) {
    unsigned r;
    asm("v_cvt_pk_bf16_f32 %0, %1, %2" : "=v"(r) : "v"(lo), "v"(hi));
    return r;
}

// C = A(Mx256) @ W(256x64-tile) + bias. 64x64 tile, 4 waves (2x2), 256 thr.
template<int MODE>
__global__ __launch_bounds__(256)
void gemm_k(const float* __restrict__ A,
            const float* __restrict__ W0, const float* __restrict__ b0,
            const float* __restrict__ W1, const float* __restrict__ b1,
            const float* __restrict__ W2, const float* __restrict__ b2,
            float* __restrict__ Fo2, bf16* __restrict__ G0,
            bf16* __restrict__ G1, bf16* __restrict__ Gt,
            float* __restrict__ Fo1, const float* __restrict__ addsrc)
{
    const int z = blockIdx.z;
    const float* W    = (z == 0) ? W0 : (z == 1) ? W1 : W2;
    const float* bias = (z == 0) ? b0 : (z == 1) ? b1 : b2;

    const int brow = blockIdx.x * 64;
    const int bcol = blockIdx.y * 64;
    const int t    = threadIdx.x;
    const int lane = t & 63;
    const int w    = t >> 6;
    const int wr   = w >> 1, wc = w & 1;
    const int g    = lane >> 4;
    const int l16  = lane & 15;

    __shared__ bf16 As[64][40];
    __shared__ bf16 Wt[64][40];

    f32x4 acc[2][2];
    #pragma unroll
    for (int i = 0; i < 2; ++i)
        #pragma unroll
        for (int j = 0; j < 2; ++j) acc[i][j] = f32x4{0.f, 0.f, 0.f, 0.f};

    const int ar = t >> 2, aj = (t & 3) * 8;
    const int wcid = t & 63, wk = (t >> 6) * 8;

    for (int k0 = 0; k0 < 256; k0 += 32) {
        {
            const float4 v0 = *(const float4*)&A[(size_t)(brow + ar)*ND + k0 + aj];
            const float4 v1 = *(const float4*)&A[(size_t)(brow + ar)*ND + k0 + aj + 4];
            bf16x8 w8 = { (bf16)v0.x, (bf16)v0.y, (bf16)v0.z, (bf16)v0.w,
                          (bf16)v1.x, (bf16)v1.y, (bf16)v1.z, (bf16)v1.w };
            *(bf16x8*)&As[ar][aj] = w8;
        }
        {
            bf16x8 w8;
            #pragma unroll
            for (int p = 0; p < 8; ++p)
                w8[p] = (bf16)W[(size_t)(k0 + wk + p)*ND + bcol + wcid];
            *(bf16x8*)&Wt[wcid][wk] = w8;
        }
        __syncthreads();

        bf16x8 af[2], bfj[2];
        #pragma unroll
        for (int i = 0; i < 2; ++i) af[i]  = *(const bf16x8*)&As[wr*32 + i*16 + l16][8*g];
        #pragma unroll
        for (int j = 0; j < 2; ++j) bfj[j] = *(const bf16x8*)&Wt[wc*32 + j*16 + l16][8*g];
        #pragma unroll
        for (int j = 0; j < 2; ++j)
            #pragma unroll
            for (int i = 0; i < 2; ++i) acc[i][j] = mfma16(af[i], bfj[j], acc[i][j]);
        __syncthreads();
    }

    #pragma unroll
    for (int j = 0; j < 2; ++j) {
        const int col = bcol + wc*32 + j*16 + l16;
        const float bj = bias[col];
        #pragma unroll
        for (int i = 0; i < 2; ++i) {
            const int row0 = brow + wr*32 + i*16 + 4*g;
            if (MODE == 1) {
                #pragma unroll
                for (int r = 0; r < 4; ++r) {
                    const size_t idx = (size_t)(row0 + r)*ND + col;
                    Fo1[idx] = addsrc[idx] + fmaxf(acc[i][j][r] + bj, 0.f);
                }
            } else if (z < 2) {
                bf16* Go = (z == 0) ? G0 : G1;
                #pragma unroll
                for (int r = 0; r < 4; ++r)
                    Go[(size_t)(row0 + r)*ND + col] = (bf16)(acc[i][j][r] + bj);
            } else {
                float vv[4];
                #pragma unroll
                for (int r = 0; r < 4; ++r) {
                    vv[r] = acc[i][j][r] + bj;
                    Fo2[(size_t)(row0 + r)*ND + col] = vv[r];
                }
                const int b2 = row0 >> 10;
                const int n0 = row0 & 1023;
                bf16x4 tv = { (bf16)vv[0], (bf16)vv[1], (bf16)vv[2], (bf16)vv[3] };
                *(bf16x4*)&Gt[((size_t)b2*ND + col)*NN + n0] = tv;
            }
        }
    }
}

// Fused attention, swapped-QK^T, zero LDS / zero barriers, 1-tile-deep
// register pipeline: K + X-chunks prefetched one tile ahead; V/pk issued at
// iteration top and consumed at PV (~100 instr of slack). Lane owns q=l16,
// m ∈ {4g+r} ∪ {16+4g+r}; X read per-lane from global through L1.
__global__ __launch_bounds__(512, 4)
void attn_k(const bf16* __restrict__ Qb, const bf16* __restrict__ Kb,
            const bf16* __restrict__ Vt, const float* __restrict__ Xpg,
            const float* __restrict__ prq, const float* __restrict__ prk,
            const float* __restrict__ Wg1, const float* __restrict__ bg1,
            const float* __restrict__ wg2, const float* __restrict__ bg2,
            float* __restrict__ Ohp, float* __restrict__ ml)
{
    const int b    = blockIdx.y;
    const int q0   = blockIdx.x * 16;
    const int z    = blockIdx.z;
    const int mb0  = z * (NN/ZSPLIT);
    const int t    = threadIdx.x;
    const int w    = t >> 6;
    const int lane = t & 63;
    const int g    = lane >> 4;
    const int l16  = lane & 15;
    const int NT   = NN/ZSPLIT/32;   // 8

    // head gate weights (uniform per wave); LOG2E folded into second layer
    float g1[3][3], gb1[3], g2v[3], gb2v;
    #pragma unroll
    for (int c = 0; c < 3; ++c)
        #pragma unroll
        for (int d = 0; d < 3; ++d) g1[c][d] = Wg1[(w*3 + c)*3 + d];
    #pragma unroll
    for (int d = 0; d < 3; ++d) { gb1[d] = bg1[w*3 + d]; g2v[d] = wg2[w*3 + d]*LOG2E; }
    gb2v = bg2[w]*LOG2E;
    const float sscale = 0.0625f * LOG2E;

    // Q as B-fragment: col=q=l16, 8 contiguous d per lane
    const bf16x8 qf = *(const bf16x8*)&Qb[((size_t)b*NN + q0 + l16)*ND + w*32 + 8*g];
    const bool okq = prq[b*NN + q0 + l16] > 0.5f;

    float m_run = -INFINITY, l_run = 0.f;
    f32x4 oh[2];
    oh[0] = f32x4{0.f,0.f,0.f,0.f};
    oh[1] = f32x4{0.f,0.f,0.f,0.f};

    // bpermute source-lane byte addresses
    const int aA = (((g & 1) * 2) * 16 + l16) * 4;
    const int aB = aA + 64;

    const bf16*  kp0 = &Kb[((size_t)b*NN + mb0 + l16)*ND + w*32 + 8*g];
    const bf16*  kp1 = kp0 + (size_t)16*ND;
    const bf16*  vp0 = &Vt[((size_t)b*ND + w*32 + l16)*NN + mb0 + 8*g];
    const bf16*  vp1 = vp0 + (size_t)16*NN;
    const float* xpl = &Xpg[(((size_t)b*NN + q0 + l16)*NN + mb0)*3];
    const float* pkp = &prk[(size_t)b*NN + mb0];

    // ---- prologue: tile-0 K fragments + X chunks ----
    bf16x8 kf0 = *(const bf16x8*)kp0;
    bf16x8 kf1 = *(const bf16x8*)kp1;
    const float* xc0p = xpl + (size_t)(4*g)*3;
    float4 c0 = *(const float4*)(xc0p);
    float4 c1 = *(const float4*)(xc0p + 4);
    float4 c2 = *(const float4*)(xc0p + 8);
    const float* xd0p = xpl + (size_t)(16 + 4*g)*3;
    float4 d0 = *(const float4*)(xd0p);
    float4 d1 = *(const float4*)(xd0p + 4);
    float4 d2 = *(const float4*)(xd0p + 8);

    #pragma unroll 1
    for (int it = 0; it < NT; ++it) {
        const int m0 = it * 32;

        // early-issue current-tile V + pk (consumed at PV / mask)
        const bf16x8 vf0 = *(const bf16x8*)(vp0 + m0);
        const bf16x8 vf1 = *(const bf16x8*)(vp1 + m0);
        const float4 pka = *(const float4*)&pkp[m0 + 4*g];
        const float4 pkb = *(const float4*)&pkp[m0 + 16 + 4*g];

        // prefetch next-tile K + X into rotation registers
        bf16x8 kn0, kn1;
        float4 nc0, nc1, nc2, nd0, nd1, nd2;
        if (it + 1 < NT) {
            const int off = m0 + 32;
            kn0 = *(const bf16x8*)(kp0 + (size_t)off*ND);
            kn1 = *(const bf16x8*)(kp1 + (size_t)off*ND);
            const float* nxc = xpl + (size_t)(off + 4*g)*3;
            nc0 = *(const float4*)(nxc);
            nc1 = *(const float4*)(nxc + 4);
            nc2 = *(const float4*)(nxc + 8);
            const float* nxd = xpl + (size_t)(off + 16 + 4*g)*3;
            nd0 = *(const float4*)(nxd);
            nd1 = *(const float4*)(nxd + 4);
            nd2 = *(const float4*)(nxd + 8);
        }

        // ---- swapped QK^T: rows = m, cols = q (K loaded one tile ago) ----
        const f32x4 zero = {0.f,0.f,0.f,0.f};
        f32x4 s[2];
        s[0] = mfma16(kf0, qf, zero);   // m = 4g+r
        s[1] = mfma16(kf1, qf, zero);   // m = 16+4g+r

        // ---- loc gate (packed f32) + masks; log2 domain ----
        // chunk floats f[3*r + c] = coord c of m = (mg*16+4g) + r
        float lv[2][4];
        #pragma unroll
        for (int mg = 0; mg < 2; ++mg) {
            const float4 pk4 = mg ? pkb : pka;
            const float4 e0 = mg ? d0 : c0;
            const float4 e1 = mg ? d1 : c1;
            const float4 e2 = mg ? d2 : c2;
            #pragma unroll
            for (int rp = 0; rp < 2; ++rp) {
                f32x2 vx, vy, vz;
                if (rp == 0) { vx = f32x2{e0.x, e0.w}; vy = f32x2{e0.y, e1.x}; vz = f32x2{e0.z, e1.y}; }
                else         { vx = f32x2{e1.z, e2.y}; vy = f32x2{e1.w, e2.z}; vz = f32x2{e2.x, e2.w}; }
                f32x2 h0 = fma2(vz, g1[2][0], fma2(vy, g1[1][0], fma2(vx, g1[0][0], sp2(gb1[0]))));
                f32x2 h1 = fma2(vz, g1[2][1], fma2(vy, g1[1][1], fma2(vx, g1[0][1], sp2(gb1[1]))));
                f32x2 h2 = fma2(vz, g1[2][2], fma2(vy, g1[1][2], fma2(vx, g1[0][2], sp2(gb1[2]))));
                const f32x2 zz = {0.f, 0.f};
                h0 = __builtin_elementwise_max(h0, zz);
                h1 = __builtin_elementwise_max(h1, zz);
                h2 = __builtin_elementwise_max(h2, zz);
                f32x2 loc = fma2(h2, g2v[2], fma2(h1, g2v[1], fma2(h0, g2v[0], sp2(gb2v))));
                const f32x2 s2 = { s[mg][2*rp], s[mg][2*rp+1] };
                const f32x2 y = fma2(s2, sscale, loc);
                lv[mg][2*rp]   = (okq && pk4[2*rp]   > 0.5f) ? y.x : -INFV;
                lv[mg][2*rp+1] = (okq && pk4[2*rp+1] > 0.5f) ? y.y : -INFV;
            }
        }

        // ---- defer-max online softmax ----
        float pm = fmaxf(fmaxf(fmaxf(lv[0][0], lv[0][1]), fmaxf(lv[0][2], lv[0][3])),
                         fmaxf(fmaxf(lv[1][0], lv[1][1]), fmaxf(lv[1][2], lv[1][3])));
        if (!__all((int)(pm <= m_run + RTHR2))) {
            float mx = pm;
            mx = fmaxf(mx, __shfl_xor(mx, 16));
            mx = fmaxf(mx, __shfl_xor(mx, 32));
            const float mnew = fmaxf(m_run, mx);
            const float corr = exp2f(m_run - mnew);
            l_run *= corr;
            #pragma unroll
            for (int r = 0; r < 4; ++r) { oh[0][r] *= corr; oh[1][r] *= corr; }
            m_run = mnew;
        }
        float pp0[4], pp1[4];
        #pragma unroll
        for (int r = 0; r < 4; ++r) {
            pp0[r] = exp2f(lv[0][r] - m_run);
            pp1[r] = exp2f(lv[1][r] - m_run);
        }
        l_run += (pp0[0] + pp0[1]) + (pp0[2] + pp0[3])
               + (pp1[0] + pp1[1]) + (pp1[2] + pp1[3]);

        // ---- build PV B-fragment in-register: element j <-> m = 8g+j ----
        const unsigned A0 = cvtpk(pp0[0], pp0[1]);
        const unsigned A1 = cvtpk(pp0[2], pp0[3]);
        const unsigned B0 = cvtpk(pp1[0], pp1[1]);
        const unsigned B1 = cvtpk(pp1[2], pp1[3]);
        const bool lo = (lane < 32);
        const int w0a = __builtin_amdgcn_ds_bpermute(aA, (int)A0);
        const int w0b = __builtin_amdgcn_ds_bpermute(aA, (int)B0);
        const int w1a = __builtin_amdgcn_ds_bpermute(aA, (int)A1);
        const int w1b = __builtin_amdgcn_ds_bpermute(aA, (int)B1);
        const int w2a = __builtin_amdgcn_ds_bpermute(aB, (int)A0);
        const int w2b = __builtin_amdgcn_ds_bpermute(aB, (int)B0);
        const int w3a = __builtin_amdgcn_ds_bpermute(aB, (int)A1);
        const int w3b = __builtin_amdgcn_ds_bpermute(aB, (int)B1);
        union { int i[4]; bf16x8 v; } pu;
        pu.i[0] = lo ? w0a : w0b;
        pu.i[1] = lo ? w1a : w1b;
        pu.i[2] = lo ? w2a : w2b;
        pu.i[3] = lo ? w3a : w3b;

        // ---- PV: oh^T[d][q] += V^T-frag x P-frag ----
        oh[0] = mfma16(vf0, pu.v, oh[0]);
        oh[1] = mfma16(vf1, pu.v, oh[1]);

        // ---- rotate pipeline registers ----
        if (it + 1 < NT) {
            kf0 = kn0; kf1 = kn1;
            c0 = nc0; c1 = nc1; c2 = nc2;
            d0 = nd0; d1 = nd1; d2 = nd2;
        }
    }

    // epilogue: lane holds q=l16, d = w*32 + dg*16 + 4g + r (contiguous r)
    float ls = l_run;
    ls += __shfl_xor(ls, 16);
    ls += __shfl_xor(ls, 32);
    const int n = q0 + l16;
    const size_t obase = (((size_t)z*NB + b)*NN + n)*ND + w*32;
    *(f32x4*)&Ohp[obase + 4*g]      = oh[0];
    *(f32x4*)&Ohp[obase + 16 + 4*g] = oh[1];
    if (g == 0) {
        const size_t mi = ((((size_t)z*NB + b)*NN + n)*NH + w)*2;
        ml[mi]   = m_run;
        ml[mi+1] = ls;
    }
}

// combine ZSPLIT key-quarters: O1 = Vf + (Σ oh_z w_z) / (Σ l_z w_z)
__global__ __launch_bounds__(256)
void comb_k(const float* __restrict__ Ohp, const float* __restrict__ ml,
            const float* __restrict__ Vf, float* __restrict__ O1)
{
    const int idx = blockIdx.x * 256 + threadIdx.x;
    const int dq = idx & 63;
    const int bn = idx >> 6;
    const int d0 = dq * 4;
    const int h  = dq >> 3;

    const size_t base = ((size_t)bn*NH + h)*2;
    const size_t zstr = (size_t)NB*NN*NH*2;
    float mz[ZSPLIT], lz[ZSPLIT];
    float M = -INFINITY;
    #pragma unroll
    for (int zi = 0; zi < ZSPLIT; ++zi) {
        mz[zi] = ml[base + zi*zstr];
        lz[zi] = ml[base + zi*zstr + 1];
        M = fmaxf(M, mz[zi]);
    }
    float wz[ZSPLIT], den = 0.f;
    #pragma unroll
    for (int zi = 0; zi < ZSPLIT; ++zi) {
        wz[zi] = exp2f(mz[zi] - M);
        den = fmaf(lz[zi], wz[zi], den);
    }
    const float inv = 1.f / den;

    const size_t e = (size_t)bn*ND + d0;
    f32x4 num = {0.f,0.f,0.f,0.f};
    #pragma unroll
    for (int zi = 0; zi < ZSPLIT; ++zi) {
        const f32x4 o = *(const f32x4*)&Ohp[e + (size_t)zi*NB*NN*ND];
        #pragma unroll
        for (int r = 0; r < 4; ++r) num[r] = fmaf(o[r], wz[zi], num[r]);
    }
    const f32x4 vf = *(const f32x4*)&Vf[e];
    f32x4 out;
    #pragma unroll
    for (int r = 0; r < 4; ++r) out[r] = vf[r] + num[r]*inv;
    *(f32x4*)&O1[e] = out;
}

extern "C" void kernel_launch(void* const* d_in, const int* in_sizes, int n_in,
                              void* d_out, int out_size, void* d_ws, size_t ws_size,
                              hipStream_t stream)
{
    const float* Y   = (const float*)d_in[1];
    const float* Xp  = (const float*)d_in[2];
    const float* prq = (const float*)d_in[3];
    const float* prk = (const float*)d_in[4];
    const float* Wq  = (const float*)d_in[5];
    const float* bq  = (const float*)d_in[6];
    const float* Wk  = (const float*)d_in[7];
    const float* bk  = (const float*)d_in[8];
    const float* Wv  = (const float*)d_in[9];
    const float* bv  = (const float*)d_in[10];
    const float* Wo  = (const float*)d_in[11];
    const float* bo  = (const float*)d_in[12];
    const float* Wg1 = (const float*)d_in[13];
    const float* bg1 = (const float*)d_in[14];
    const float* wg2 = (const float*)d_in[15];
    const float* bg2 = (const float*)d_in[16];
    float* out = (float*)d_out;

    const size_t BND = (size_t)NB * NN * ND;   // 1M
    float* Vf  = (float*)d_ws;                           // 4 MB
    float* Ohp = Vf + BND;                               // 16 MB (z=0..3)
    float* ml  = Ohp + (size_t)ZSPLIT*BND;               // 1 MB
    bf16*  Qb  = (bf16*)(ml + (size_t)ZSPLIT*NB*NN*NH*2);// 2 MB
    bf16*  Kb  = Qb + BND;                               // 2 MB
    bf16*  Vt  = Kb + BND;                               // 2 MB
    float* O1  = (float*)Qb;                             // aliases Qb+Kb (dead after attn)

    gemm_k<0><<<dim3(64, 4, 3), 256, 0, stream>>>(
        Y, Wq, bq, Wk, bk, Wv, bv,
        Vf, Qb, Kb, Vt, nullptr, nullptr);

    attn_k<<<dim3(NN/16, NB, ZSPLIT), 512, 0, stream>>>(
        Qb, Kb, Vt, Xp, prq, prk, Wg1, bg1, wg2, bg2, Ohp, ml);

    comb_k<<<dim3(1024), 256, 0, stream>>>(Ohp, ml, Vf, O1);

    gemm_k<1><<<dim3(64, 4, 1), 256, 0, stream>>>(
        O1, Wo, bo, Wo, bo, Wo, bo,
        nullptr, nullptr, nullptr, nullptr, out, O1);
}

// Round 11
// 107.371 us; speedup vs baseline: 1.7288x; 1.7288x over previous
//
#include <hip/hip_runtime.h>
#include <hip/hip_bf16.h>
#include <math.h>

typedef __bf16 bf16;
typedef __bf16 bf16x4 __attribute__((ext_vector_type(4)));
typedef __bf16 bf16x8 __attribute__((ext_vector_type(8)));
typedef float f32x2 __attribute__((ext_vector_type(2)));
typedef float f32x4 __attribute__((ext_vector_type(4)));

#define NB 4
#define NN 1024
#define ND 256
#define NH 8
#define INFV 1e38f
#define RTHR2 11.5f          // defer-max threshold, log2 domain (~e^8)
#define LOG2E 1.44269504f
#define ZSPLIT 4

__device__ __forceinline__ f32x4 mfma16(bf16x8 a, bf16x8 b, f32x4 c) {
    return __builtin_amdgcn_mfma_f32_16x16x32_bf16(a, b, c, 0, 0, 0);
}
__device__ __forceinline__ f32x2 sp2(float v) { return f32x2{v, v}; }
__device__ __forceinline__ f32x2 fma2(f32x2 a, float b, f32x2 c) {
    return __builtin_elementwise_fma(a, sp2(b), c);
}
__device__ __forceinline__ unsigned cvtpk(float lo, float hi) {
    unsigned r;
    asm("v_cvt_pk_bf16_f32 %0, %1, %2" : "=v"(r) : "v"(lo), "v"(hi));
    return r;
}
// force a wave-uniform float into an SGPR
__device__ __forceinline__ float rfl(float x) {
    return __int_as_float(__builtin_amdgcn_readfirstlane(__float_as_int(x)));
}

// C = A(Mx256) @ W(256x64-tile) + bias. 64x64 tile, 4 waves (2x2), 256 thr.
template<int MODE>
__global__ __launch_bounds__(256)
void gemm_k(const float* __restrict__ A,
            const float* __restrict__ W0, const float* __restrict__ b0,
            const float* __restrict__ W1, const float* __restrict__ b1,
            const float* __restrict__ W2, const float* __restrict__ b2,
            float* __restrict__ Fo2, bf16* __restrict__ G0,
            bf16* __restrict__ G1, bf16* __restrict__ Gt,
            float* __restrict__ Fo1, const float* __restrict__ addsrc)
{
    const int z = blockIdx.z;
    const float* W    = (z == 0) ? W0 : (z == 1) ? W1 : W2;
    const float* bias = (z == 0) ? b0 : (z == 1) ? b1 : b2;

    const int brow = blockIdx.x * 64;
    const int bcol = blockIdx.y * 64;
    const int t    = threadIdx.x;
    const int lane = t & 63;
    const int w    = t >> 6;
    const int wr   = w >> 1, wc = w & 1;
    const int g    = lane >> 4;
    const int l16  = lane & 15;

    __shared__ bf16 As[64][40];
    __shared__ bf16 Wt[64][40];

    f32x4 acc[2][2];
    #pragma unroll
    for (int i = 0; i < 2; ++i)
        #pragma unroll
        for (int j = 0; j < 2; ++j) acc[i][j] = f32x4{0.f, 0.f, 0.f, 0.f};

    const int ar = t >> 2, aj = (t & 3) * 8;
    const int wcid = t & 63, wk = (t >> 6) * 8;

    for (int k0 = 0; k0 < 256; k0 += 32) {
        {
            const float4 v0 = *(const float4*)&A[(size_t)(brow + ar)*ND + k0 + aj];
            const float4 v1 = *(const float4*)&A[(size_t)(brow + ar)*ND + k0 + aj + 4];
            bf16x8 w8 = { (bf16)v0.x, (bf16)v0.y, (bf16)v0.z, (bf16)v0.w,
                          (bf16)v1.x, (bf16)v1.y, (bf16)v1.z, (bf16)v1.w };
            *(bf16x8*)&As[ar][aj] = w8;
        }
        {
            bf16x8 w8;
            #pragma unroll
            for (int p = 0; p < 8; ++p)
                w8[p] = (bf16)W[(size_t)(k0 + wk + p)*ND + bcol + wcid];
            *(bf16x8*)&Wt[wcid][wk] = w8;
        }
        __syncthreads();

        bf16x8 af[2], bfj[2];
        #pragma unroll
        for (int i = 0; i < 2; ++i) af[i]  = *(const bf16x8*)&As[wr*32 + i*16 + l16][8*g];
        #pragma unroll
        for (int j = 0; j < 2; ++j) bfj[j] = *(const bf16x8*)&Wt[wc*32 + j*16 + l16][8*g];
        #pragma unroll
        for (int j = 0; j < 2; ++j)
            #pragma unroll
            for (int i = 0; i < 2; ++i) acc[i][j] = mfma16(af[i], bfj[j], acc[i][j]);
        __syncthreads();
    }

    #pragma unroll
    for (int j = 0; j < 2; ++j) {
        const int col = bcol + wc*32 + j*16 + l16;
        const float bj = bias[col];
        #pragma unroll
        for (int i = 0; i < 2; ++i) {
            const int row0 = brow + wr*32 + i*16 + 4*g;
            if (MODE == 1) {
                #pragma unroll
                for (int r = 0; r < 4; ++r) {
                    const size_t idx = (size_t)(row0 + r)*ND + col;
                    Fo1[idx] = addsrc[idx] + fmaxf(acc[i][j][r] + bj, 0.f);
                }
            } else if (z < 2) {
                bf16* Go = (z == 0) ? G0 : G1;
                #pragma unroll
                for (int r = 0; r < 4; ++r)
                    Go[(size_t)(row0 + r)*ND + col] = (bf16)(acc[i][j][r] + bj);
            } else {
                float vv[4];
                #pragma unroll
                for (int r = 0; r < 4; ++r) {
                    vv[r] = acc[i][j][r] + bj;
                    Fo2[(size_t)(row0 + r)*ND + col] = vv[r];
                }
                const int b2 = row0 >> 10;
                const int n0 = row0 & 1023;
                bf16x4 tv = { (bf16)vv[0], (bf16)vv[1], (bf16)vv[2], (bf16)vv[3] };
                *(bf16x4*)&Gt[((size_t)b2*ND + col)*NN + n0] = tv;
            }
        }
    }
}

// Fused attention, swapped-QK^T, zero LDS / zero barriers.
// Pipeline (fits 128-VGPR cap): K + mg0-X prefetched one tile ahead;
// mg1-X / V / pk issued at iteration top, consumed mid/late iteration.
// Gate weights in SGPRs via readfirstlane. launch_bounds(512,2):
// empirical VGPR cap = 256/N (R5: N=8 -> 32; R10: N=4 -> 64 + spills).
__global__ __launch_bounds__(512, 2)
void attn_k(const bf16* __restrict__ Qb, const bf16* __restrict__ Kb,
            const bf16* __restrict__ Vt, const float* __restrict__ Xpg,
            const float* __restrict__ prq, const float* __restrict__ prk,
            const float* __restrict__ Wg1, const float* __restrict__ bg1,
            const float* __restrict__ wg2, const float* __restrict__ bg2,
            float* __restrict__ Ohp, float* __restrict__ ml)
{
    const int b    = blockIdx.y;
    const int q0   = blockIdx.x * 16;
    const int z    = blockIdx.z;
    const int mb0  = z * (NN/ZSPLIT);
    const int t    = threadIdx.x;
    const int w    = t >> 6;
    const int lane = t & 63;
    const int g    = lane >> 4;
    const int l16  = lane & 15;
    const int NT   = NN/ZSPLIT/32;   // 8

    // head gate weights -> SGPRs (wave-uniform); LOG2E folded in
    float g1[3][3], gb1[3], g2v[3], gb2v;
    #pragma unroll
    for (int c = 0; c < 3; ++c)
        #pragma unroll
        for (int d = 0; d < 3; ++d) g1[c][d] = rfl(Wg1[(w*3 + c)*3 + d]);
    #pragma unroll
    for (int d = 0; d < 3; ++d) {
        gb1[d] = rfl(bg1[w*3 + d]);
        g2v[d] = rfl(wg2[w*3 + d]*LOG2E);
    }
    gb2v = rfl(bg2[w]*LOG2E);
    const float sscale = 0.0625f * LOG2E;

    // Q as B-fragment: col=q=l16, 8 contiguous d per lane
    const bf16x8 qf = *(const bf16x8*)&Qb[((size_t)b*NN + q0 + l16)*ND + w*32 + 8*g];
    const bool okq = prq[b*NN + q0 + l16] > 0.5f;

    float m_run = -INFINITY, l_run = 0.f;
    f32x4 oh[2];
    oh[0] = f32x4{0.f,0.f,0.f,0.f};
    oh[1] = f32x4{0.f,0.f,0.f,0.f};

    // bpermute source-lane byte addresses
    const int aA = (((g & 1) * 2) * 16 + l16) * 4;
    const int aB = aA + 64;

    const bf16*  kp0 = &Kb[((size_t)b*NN + mb0 + l16)*ND + w*32 + 8*g];
    const bf16*  kp1 = kp0 + (size_t)16*ND;
    const bf16*  vp0 = &Vt[((size_t)b*ND + w*32 + l16)*NN + mb0 + 8*g];
    const bf16*  vp1 = vp0 + (size_t)16*NN;
    const float* xpl = &Xpg[(((size_t)b*NN + q0 + l16)*NN + mb0)*3];
    const float* pkp = &prk[(size_t)b*NN + mb0];

    // ---- prologue: tile-0 K fragments + mg0 X chunks ----
    bf16x8 kf0 = *(const bf16x8*)kp0;
    bf16x8 kf1 = *(const bf16x8*)kp1;
    const float* xc0p = xpl + (size_t)(4*g)*3;
    float4 c0 = *(const float4*)(xc0p);
    float4 c1 = *(const float4*)(xc0p + 4);
    float4 c2 = *(const float4*)(xc0p + 8);

    #pragma unroll 1
    for (int it = 0; it < NT; ++it) {
        const int m0 = it * 32;

        // ---- current-tile loads: V (consumed at PV), pk (mask), mg1 X (gate) ----
        const bf16x8 vf0 = *(const bf16x8*)(vp0 + m0);
        const bf16x8 vf1 = *(const bf16x8*)(vp1 + m0);
        const float4 pka = *(const float4*)&pkp[m0 + 4*g];
        const float4 pkb = *(const float4*)&pkp[m0 + 16 + 4*g];
        const float* xd = xpl + (size_t)(m0 + 16 + 4*g)*3;
        const float4 d0 = *(const float4*)(xd);
        const float4 d1 = *(const float4*)(xd + 4);
        const float4 d2 = *(const float4*)(xd + 8);

        // ---- next-tile prefetch: K + mg0 X ----
        bf16x8 kn0, kn1;
        float4 nc0, nc1, nc2;
        if (it + 1 < NT) {
            const int off = m0 + 32;
            kn0 = *(const bf16x8*)(kp0 + (size_t)off*ND);
            kn1 = *(const bf16x8*)(kp1 + (size_t)off*ND);
            const float* nxc = xpl + (size_t)(off + 4*g)*3;
            nc0 = *(const float4*)(nxc);
            nc1 = *(const float4*)(nxc + 4);
            nc2 = *(const float4*)(nxc + 8);
        }

        // ---- swapped QK^T: rows = m, cols = q (K loaded one tile ago) ----
        const f32x4 zero = {0.f,0.f,0.f,0.f};
        f32x4 s[2];
        s[0] = mfma16(kf0, qf, zero);   // m = 4g+r
        s[1] = mfma16(kf1, qf, zero);   // m = 16+4g+r

        // ---- loc gate (packed f32) + masks; log2 domain ----
        // chunk floats f[3*r + c] = coord c of m = (mg*16+4g) + r
        float lv[2][4];
        #pragma unroll
        for (int mg = 0; mg < 2; ++mg) {
            const float4 pk4 = mg ? pkb : pka;
            const float4 e0 = mg ? d0 : c0;
            const float4 e1 = mg ? d1 : c1;
            const float4 e2 = mg ? d2 : c2;
            #pragma unroll
            for (int rp = 0; rp < 2; ++rp) {
                f32x2 vx, vy, vz;
                if (rp == 0) { vx = f32x2{e0.x, e0.w}; vy = f32x2{e0.y, e1.x}; vz = f32x2{e0.z, e1.y}; }
                else         { vx = f32x2{e1.z, e2.y}; vy = f32x2{e1.w, e2.z}; vz = f32x2{e2.x, e2.w}; }
                f32x2 h0 = fma2(vz, g1[2][0], fma2(vy, g1[1][0], fma2(vx, g1[0][0], sp2(gb1[0]))));
                f32x2 h1 = fma2(vz, g1[2][1], fma2(vy, g1[1][1], fma2(vx, g1[0][1], sp2(gb1[1]))));
                f32x2 h2 = fma2(vz, g1[2][2], fma2(vy, g1[1][2], fma2(vx, g1[0][2], sp2(gb1[2]))));
                const f32x2 zz = {0.f, 0.f};
                h0 = __builtin_elementwise_max(h0, zz);
                h1 = __builtin_elementwise_max(h1, zz);
                h2 = __builtin_elementwise_max(h2, zz);
                f32x2 loc = fma2(h2, g2v[2], fma2(h1, g2v[1], fma2(h0, g2v[0], sp2(gb2v))));
                const f32x2 s2 = { s[mg][2*rp], s[mg][2*rp+1] };
                const f32x2 y = fma2(s2, sscale, loc);
                lv[mg][2*rp]   = (okq && pk4[2*rp]   > 0.5f) ? y.x : -INFV;
                lv[mg][2*rp+1] = (okq && pk4[2*rp+1] > 0.5f) ? y.y : -INFV;
            }
        }

        // ---- defer-max online softmax ----
        float pm = fmaxf(fmaxf(fmaxf(lv[0][0], lv[0][1]), fmaxf(lv[0][2], lv[0][3])),
                         fmaxf(fmaxf(lv[1][0], lv[1][1]), fmaxf(lv[1][2], lv[1][3])));
        if (!__all((int)(pm <= m_run + RTHR2))) {
            float mx = pm;
            mx = fmaxf(mx, __shfl_xor(mx, 16));
            mx = fmaxf(mx, __shfl_xor(mx, 32));
            const float mnew = fmaxf(m_run, mx);
            const float corr = exp2f(m_run - mnew);
            l_run *= corr;
            #pragma unroll
            for (int r = 0; r < 4; ++r) { oh[0][r] *= corr; oh[1][r] *= corr; }
            m_run = mnew;
        }
        float pp0[4], pp1[4];
        #pragma unroll
        for (int r = 0; r < 4; ++r) {
            pp0[r] = exp2f(lv[0][r] - m_run);
            pp1[r] = exp2f(lv[1][r] - m_run);
        }
        l_run += (pp0[0] + pp0[1]) + (pp0[2] + pp0[3])
               + (pp1[0] + pp1[1]) + (pp1[2] + pp1[3]);

        // ---- build PV B-fragment in-register: element j <-> m = 8g+j ----
        const unsigned A0 = cvtpk(pp0[0], pp0[1]);
        const unsigned A1 = cvtpk(pp0[2], pp0[3]);
        const unsigned B0 = cvtpk(pp1[0], pp1[1]);
        const unsigned B1 = cvtpk(pp1[2], pp1[3]);
        const bool lo = (lane < 32);
        const int w0a = __builtin_amdgcn_ds_bpermute(aA, (int)A0);
        const int w0b = __builtin_amdgcn_ds_bpermute(aA, (int)B0);
        const int w1a = __builtin_amdgcn_ds_bpermute(aA, (int)A1);
        const int w1b = __builtin_amdgcn_ds_bpermute(aA, (int)B1);
        const int w2a = __builtin_amdgcn_ds_bpermute(aB, (int)A0);
        const int w2b = __builtin_amdgcn_ds_bpermute(aB, (int)B0);
        const int w3a = __builtin_amdgcn_ds_bpermute(aB, (int)A1);
        const int w3b = __builtin_amdgcn_ds_bpermute(aB, (int)B1);
        union { int i[4]; bf16x8 v; } pu;
        pu.i[0] = lo ? w0a : w0b;
        pu.i[1] = lo ? w1a : w1b;
        pu.i[2] = lo ? w2a : w2b;
        pu.i[3] = lo ? w3a : w3b;

        // ---- PV: oh^T[d][q] += V^T-frag x P-frag ----
        oh[0] = mfma16(vf0, pu.v, oh[0]);
        oh[1] = mfma16(vf1, pu.v, oh[1]);

        // ---- rotate pipeline registers ----
        if (it + 1 < NT) {
            kf0 = kn0; kf1 = kn1;
            c0 = nc0; c1 = nc1; c2 = nc2;
        }
    }

    // epilogue: lane holds q=l16, d = w*32 + dg*16 + 4g + r (contiguous r)
    float ls = l_run;
    ls += __shfl_xor(ls, 16);
    ls += __shfl_xor(ls, 32);
    const int n = q0 + l16;
    const size_t obase = (((size_t)z*NB + b)*NN + n)*ND + w*32;
    *(f32x4*)&Ohp[obase + 4*g]      = oh[0];
    *(f32x4*)&Ohp[obase + 16 + 4*g] = oh[1];
    if (g == 0) {
        const size_t mi = ((((size_t)z*NB + b)*NN + n)*NH + w)*2;
        ml[mi]   = m_run;
        ml[mi+1] = ls;
    }
}

// combine ZSPLIT key-quarters: O1 = Vf + (Σ oh_z w_z) / (Σ l_z w_z)
__global__ __launch_bounds__(256)
void comb_k(const float* __restrict__ Ohp, const float* __restrict__ ml,
            const float* __restrict__ Vf, float* __restrict__ O1)
{
    const int idx = blockIdx.x * 256 + threadIdx.x;
    const int dq = idx & 63;
    const int bn = idx >> 6;
    const int d0 = dq * 4;
    const int h  = dq >> 3;

    const size_t base = ((size_t)bn*NH + h)*2;
    const size_t zstr = (size_t)NB*NN*NH*2;
    float mz[ZSPLIT], lz[ZSPLIT];
    float M = -INFINITY;
    #pragma unroll
    for (int zi = 0; zi < ZSPLIT; ++zi) {
        mz[zi] = ml[base + zi*zstr];
        lz[zi] = ml[base + zi*zstr + 1];
        M = fmaxf(M, mz[zi]);
    }
    float wz[ZSPLIT], den = 0.f;
    #pragma unroll
    for (int zi = 0; zi < ZSPLIT; ++zi) {
        wz[zi] = exp2f(mz[zi] - M);
        den = fmaf(lz[zi], wz[zi], den);
    }
    const float inv = 1.f / den;

    const size_t e = (size_t)bn*ND + d0;
    f32x4 num = {0.f,0.f,0.f,0.f};
    #pragma unroll
    for (int zi = 0; zi < ZSPLIT; ++zi) {
        const f32x4 o = *(const f32x4*)&Ohp[e + (size_t)zi*NB*NN*ND];
        #pragma unroll
        for (int r = 0; r < 4; ++r) num[r] = fmaf(o[r], wz[zi], num[r]);
    }
    const f32x4 vf = *(const f32x4*)&Vf[e];
    f32x4 out;
    #pragma unroll
    for (int r = 0; r < 4; ++r) out[r] = vf[r] + num[r]*inv;
    *(f32x4*)&O1[e] = out;
}

extern "C" void kernel_launch(void* const* d_in, const int* in_sizes, int n_in,
                              void* d_out, int out_size, void* d_ws, size_t ws_size,
                              hipStream_t stream)
{
    const float* Y   = (const float*)d_in[1];
    const float* Xp  = (const float*)d_in[2];
    const float* prq = (const float*)d_in[3];
    const float* prk = (const float*)d_in[4];
    const float* Wq  = (const float*)d_in[5];
    const float* bq  = (const float*)d_in[6];
    const float* Wk  = (const float*)d_in[7];
    const float* bk  = (const float*)d_in[8];
    const float* Wv  = (const float*)d_in[9];
    const float* bv  = (const float*)d_in[10];
    const float* Wo  = (const float*)d_in[11];
    const float* bo  = (const float*)d_in[12];
    const float* Wg1 = (const float*)d_in[13];
    const float* bg1 = (const float*)d_in[14];
    const float* wg2 = (const float*)d_in[15];
    const float* bg2 = (const float*)d_in[16];
    float* out = (float*)d_out;

    const size_t BND = (size_t)NB * NN * ND;   // 1M
    float* Vf  = (float*)d_ws;                           // 4 MB
    float* Ohp = Vf + BND;                               // 16 MB (z=0..3)
    float* ml  = Ohp + (size_t)ZSPLIT*BND;               // 1 MB
    bf16*  Qb  = (bf16*)(ml + (size_t)ZSPLIT*NB*NN*NH*2);// 2 MB
    bf16*  Kb  = Qb + BND;                               // 2 MB
    bf16*  Vt  = Kb + BND;                               // 2 MB
    float* O1  = (float*)Qb;                             // aliases Qb+Kb (dead after attn)

    gemm_k<0><<<dim3(64, 4, 3), 256, 0, stream>>>(
        Y, Wq, bq, Wk, bk, Wv, bv,
        Vf, Qb, Kb, Vt, nullptr, nullptr);

    attn_k<<<dim3(NN/16, NB, ZSPLIT), 512, 0, stream>>>(
        Qb, Kb, Vt, Xp, prq, prk, Wg1, bg1, wg2, bg2, Ohp, ml);

    comb_k<<<dim3(1024), 256, 0, stream>>>(Ohp, ml, Vf, O1);

    gemm_k<1><<<dim3(64, 4, 1), 256, 0, stream>>>(
        O1, Wo, bo, Wo, bo, Wo, bo,
        nullptr, nullptr, nullptr, nullptr, out, O1);
}

// Round 12
// 71.354 us; speedup vs baseline: 2.6015x; 1.5048x over previous
//
#include <hip/hip_runtime.h>
#include <hip/hip_bf16.h>
#include <math.h>

typedef __bf16 bf16;
typedef __bf16 bf16x4 __attribute__((ext_vector_type(4)));
typedef __bf16 bf16x8 __attribute__((ext_vector_type(8)));
typedef float f32x2 __attribute__((ext_vector_type(2)));
typedef float f32x4 __attribute__((ext_vector_type(4)));

#define NB 4
#define NN 1024
#define ND 256
#define NH 8
#define INFV 1e38f
#define RTHR2 11.5f          // defer-max threshold, log2 domain (~e^8)
#define LOG2E 1.44269504f
#define ZSPLIT 4

__device__ __forceinline__ f32x4 mfma16(bf16x8 a, bf16x8 b, f32x4 c) {
    return __builtin_amdgcn_mfma_f32_16x16x32_bf16(a, b, c, 0, 0, 0);
}
__device__ __forceinline__ f32x2 sp2(float v) { return f32x2{v, v}; }
__device__ __forceinline__ f32x2 fma2(f32x2 a, float b, f32x2 c) {
    return __builtin_elementwise_fma(a, sp2(b), c);
}

// C = A(Mx256) @ W(256x64-tile) + bias. 64x64 tile, 4 waves (2x2), 256 thr.
template<int MODE>
__global__ __launch_bounds__(256)
void gemm_k(const float* __restrict__ A,
            const float* __restrict__ W0, const float* __restrict__ b0,
            const float* __restrict__ W1, const float* __restrict__ b1,
            const float* __restrict__ W2, const float* __restrict__ b2,
            float* __restrict__ Fo2, bf16* __restrict__ G0,
            bf16* __restrict__ G1, bf16* __restrict__ Gt,
            float* __restrict__ Fo1, const float* __restrict__ addsrc)
{
    const int z = blockIdx.z;
    const float* W    = (z == 0) ? W0 : (z == 1) ? W1 : W2;
    const float* bias = (z == 0) ? b0 : (z == 1) ? b1 : b2;

    const int brow = blockIdx.x * 64;
    const int bcol = blockIdx.y * 64;
    const int t    = threadIdx.x;
    const int lane = t & 63;
    const int w    = t >> 6;
    const int wr   = w >> 1, wc = w & 1;
    const int g    = lane >> 4;
    const int l16  = lane & 15;

    __shared__ bf16 As[64][40];
    __shared__ bf16 Wt[64][40];

    f32x4 acc[2][2];
    #pragma unroll
    for (int i = 0; i < 2; ++i)
        #pragma unroll
        for (int j = 0; j < 2; ++j) acc[i][j] = f32x4{0.f, 0.f, 0.f, 0.f};

    const int ar = t >> 2, aj = (t & 3) * 8;
    const int wcid = t & 63, wk = (t >> 6) * 8;

    for (int k0 = 0; k0 < 256; k0 += 32) {
        {
            const float4 v0 = *(const float4*)&A[(size_t)(brow + ar)*ND + k0 + aj];
            const float4 v1 = *(const float4*)&A[(size_t)(brow + ar)*ND + k0 + aj + 4];
            bf16x8 w8 = { (bf16)v0.x, (bf16)v0.y, (bf16)v0.z, (bf16)v0.w,
                          (bf16)v1.x, (bf16)v1.y, (bf16)v1.z, (bf16)v1.w };
            *(bf16x8*)&As[ar][aj] = w8;
        }
        {
            bf16x8 w8;
            #pragma unroll
            for (int p = 0; p < 8; ++p)
                w8[p] = (bf16)W[(size_t)(k0 + wk + p)*ND + bcol + wcid];
            *(bf16x8*)&Wt[wcid][wk] = w8;
        }
        __syncthreads();

        bf16x8 af[2], bfj[2];
        #pragma unroll
        for (int i = 0; i < 2; ++i) af[i]  = *(const bf16x8*)&As[wr*32 + i*16 + l16][8*g];
        #pragma unroll
        for (int j = 0; j < 2; ++j) bfj[j] = *(const bf16x8*)&Wt[wc*32 + j*16 + l16][8*g];
        #pragma unroll
        for (int j = 0; j < 2; ++j)
            #pragma unroll
            for (int i = 0; i < 2; ++i) acc[i][j] = mfma16(af[i], bfj[j], acc[i][j]);
        __syncthreads();
    }

    #pragma unroll
    for (int j = 0; j < 2; ++j) {
        const int col = bcol + wc*32 + j*16 + l16;
        const float bj = bias[col];
        #pragma unroll
        for (int i = 0; i < 2; ++i) {
            const int row0 = brow + wr*32 + i*16 + 4*g;
            if (MODE == 1) {
                #pragma unroll
                for (int r = 0; r < 4; ++r) {
                    const size_t idx = (size_t)(row0 + r)*ND + col;
                    Fo1[idx] = addsrc[idx] + fmaxf(acc[i][j][r] + bj, 0.f);
                }
            } else if (z < 2) {
                bf16* Go = (z == 0) ? G0 : G1;
                #pragma unroll
                for (int r = 0; r < 4; ++r)
                    Go[(size_t)(row0 + r)*ND + col] = (bf16)(acc[i][j][r] + bj);
            } else {
                float vv[4];
                #pragma unroll
                for (int r = 0; r < 4; ++r) {
                    vv[r] = acc[i][j][r] + bj;
                    Fo2[(size_t)(row0 + r)*ND + col] = vv[r];
                }
                const int b2 = row0 >> 10;
                const int n0 = row0 & 1023;
                bf16x4 tv = { (bf16)vv[0], (bf16)vv[1], (bf16)vv[2], (bf16)vv[3] };
                *(bf16x4*)&Gt[((size_t)b2*ND + col)*NN + n0] = tv;
            }
        }
    }
}

// Fused attention — R6 structure (best measured) with head-split blocks:
// 256 thr = 4 waves = 4 heads; grid.y = batch*2 (head-half). X_pairs staged
// cooperatively in LDS (double-buffered); K/V/X/pk register-prefetched one
// tile ahead; P transposed through wave-private LDS. launch_bounds(256,4):
// VGPR cap 128 (R6 needed ~70) -> no spills; LDS 22KB -> ~7 blocks/CU.
__global__ __launch_bounds__(256, 4)
void attn_k(const bf16* __restrict__ Qb, const bf16* __restrict__ Kb,
            const bf16* __restrict__ Vt, const float* __restrict__ Xpg,
            const float* __restrict__ prq, const float* __restrict__ prk,
            const float* __restrict__ Wg1, const float* __restrict__ bg1,
            const float* __restrict__ wg2, const float* __restrict__ bg2,
            float* __restrict__ Ohp, float* __restrict__ ml)
{
    const int yb   = blockIdx.y;
    const int b    = yb >> 1;
    const int hg   = yb & 1;
    const int q0   = blockIdx.x * 16;
    const int z    = blockIdx.z;
    const int mb0  = z * (NN/ZSPLIT);
    const int t    = threadIdx.x;
    const int w    = t >> 6;        // wave 0..3
    const int h    = hg*4 + w;      // head 0..7
    const int lane = t & 63;
    const int g    = lane >> 4;
    const int l16  = lane & 15;
    const int NT   = NN/ZSPLIT/32;  // 8

    __shared__ float Xps[2][16*132];
    __shared__ bf16  Ps[4][16][40];

    // head gate weights (uniform per wave); LOG2E folded into second layer
    float g1[3][3], gb1[3], g2v[3], gb2v;
    #pragma unroll
    for (int c = 0; c < 3; ++c)
        #pragma unroll
        for (int d = 0; d < 3; ++d) g1[c][d] = Wg1[(h*3 + c)*3 + d];
    #pragma unroll
    for (int d = 0; d < 3; ++d) { gb1[d] = bg1[h*3 + d]; g2v[d] = wg2[h*3 + d]*LOG2E; }
    gb2v = bg2[h]*LOG2E;
    const float sscale = 0.0625f * LOG2E;

    const bf16x8 qf = *(const bf16x8*)&Qb[((size_t)b*NN + q0 + l16)*ND + h*32 + 8*g];

    bool okq[4];
    #pragma unroll
    for (int r = 0; r < 4; ++r)
        okq[r] = prq[b*NN + q0 + 4*g + r] > 0.5f;

    float m_run[4], l_run[4];   // log2-domain max; per-lane partial sum
    f32x4 oh[2];
    #pragma unroll
    for (int r = 0; r < 4; ++r) { m_run[r] = -INFINITY; l_run[r] = 0.f; }
    oh[0] = f32x4{0.f,0.f,0.f,0.f};
    oh[1] = f32x4{0.f,0.f,0.f,0.f};

    const bf16*  kp0 = &Kb[((size_t)b*NN + mb0 + l16)*ND + h*32 + 8*g];
    const bf16*  kp1 = kp0 + (size_t)16*ND;
    const bf16*  vp0 = &Vt[((size_t)b*ND + h*32 + l16)*NN + mb0 + 8*g];
    const bf16*  vp1 = vp0 + (size_t)16*NN;
    const int    xq  = t >> 5, xm = t & 31;   // xq 0..7; stage rows xq and xq+8
    const float* xppA = &Xpg[(((size_t)b*NN + q0 + xq)*NN + mb0 + xm)*3];
    const float* xppB = &Xpg[(((size_t)b*NN + q0 + xq + 8)*NN + mb0 + xm)*3];
    const float* pkp  = &prk[(size_t)b*NN + mb0 + l16];

    // ---- prologue: tile-0 fragments + Xps[0] ----
    bf16x8 kf0 = *(const bf16x8*)kp0;
    bf16x8 kf1 = *(const bf16x8*)kp1;
    bf16x8 vf0 = *(const bf16x8*)vp0;
    bf16x8 vf1 = *(const bf16x8*)vp1;
    float xxA = xppA[0], xyA = xppA[1], xzA = xppA[2];
    float xxB = xppB[0], xyB = xppB[1], xzB = xppB[2];
    float pk0 = pkp[0], pk1 = pkp[16];
    {
        float* dA = &Xps[0][xq*132 + xm*4];
        dA[0] = xxA; dA[1] = xyA; dA[2] = xzA;
        float* dB = &Xps[0][(xq + 8)*132 + xm*4];
        dB[0] = xxB; dB[1] = xyB; dB[2] = xzB;
    }
    __syncthreads();

    for (int it = 0; it < NT; ++it) {
        const int cur = it & 1;

        // issue next-tile loads (consumed next iter)
        bf16x8 kn0, kn1, vn0, vn1;
        float  xnxA, xnyA, xnzA, xnxB, xnyB, xnzB, pn0, pn1;
        if (it + 1 < NT) {
            const int off = (it + 1) * 32;
            kn0 = *(const bf16x8*)(kp0 + (size_t)off*ND);
            kn1 = *(const bf16x8*)(kp1 + (size_t)off*ND);
            vn0 = *(const bf16x8*)(vp0 + off);
            vn1 = *(const bf16x8*)(vp1 + off);
            xnxA = xppA[(size_t)off*3];
            xnyA = xppA[(size_t)off*3 + 1];
            xnzA = xppA[(size_t)off*3 + 2];
            xnxB = xppB[(size_t)off*3];
            xnyB = xppB[(size_t)off*3 + 1];
            xnzB = xppB[(size_t)off*3 + 2];
            pn0 = pkp[off]; pn1 = pkp[off + 16];
        }

        // QK^T
        const f32x4 zero = {0.f,0.f,0.f,0.f};
        f32x4 s[2];
        s[0] = mfma16(qf, kf0, zero);
        s[1] = mfma16(qf, kf1, zero);

        const bool okk0 = pk0 > 0.5f;
        const bool okk1 = pk1 > 0.5f;

        // loc gate (packed f32 over r-pairs) + masks; log2 domain
        float lv[2][4];
        #pragma unroll
        for (int mg = 0; mg < 2; ++mg) {
            const bool okkm = mg ? okk1 : okk0;
            const int m = mg*16 + l16;
            #pragma unroll
            for (int rp = 0; rp < 2; ++rp) {
                const int q = 4*g + 2*rp;
                const float4 xa = *(const float4*)&Xps[cur][q*132 + m*4];
                const float4 xb = *(const float4*)&Xps[cur][(q+1)*132 + m*4];
                const f32x2 vx = {xa.x, xb.x};
                const f32x2 vy = {xa.y, xb.y};
                const f32x2 vz = {xa.z, xb.z};
                f32x2 h0 = fma2(vz, g1[2][0], fma2(vy, g1[1][0], fma2(vx, g1[0][0], sp2(gb1[0]))));
                f32x2 h1 = fma2(vz, g1[2][1], fma2(vy, g1[1][1], fma2(vx, g1[0][1], sp2(gb1[1]))));
                f32x2 h2 = fma2(vz, g1[2][2], fma2(vy, g1[1][2], fma2(vx, g1[0][2], sp2(gb1[2]))));
                const f32x2 zz = {0.f, 0.f};
                h0 = __builtin_elementwise_max(h0, zz);
                h1 = __builtin_elementwise_max(h1, zz);
                h2 = __builtin_elementwise_max(h2, zz);
                f32x2 loc = fma2(h2, g2v[2], fma2(h1, g2v[1], fma2(h0, g2v[0], sp2(gb2v))));
                const f32x2 s2 = { s[mg][2*rp], s[mg][2*rp+1] };
                const f32x2 y = fma2(s2, sscale, loc);
                lv[mg][2*rp]   = (okq[2*rp]   && okkm) ? y.x : -INFV;
                lv[mg][2*rp+1] = (okq[2*rp+1] && okkm) ? y.y : -INFV;
            }
        }

        // defer-max online softmax (log2 domain)
        float pm[4];
        #pragma unroll
        for (int r = 0; r < 4; ++r) pm[r] = fmaxf(lv[0][r], lv[1][r]);
        const bool cond = (pm[0] <= m_run[0] + RTHR2) && (pm[1] <= m_run[1] + RTHR2)
                       && (pm[2] <= m_run[2] + RTHR2) && (pm[3] <= m_run[3] + RTHR2);
        if (!__all((int)cond)) {
            #pragma unroll
            for (int r = 0; r < 4; ++r) {
                float mx = pm[r];
                mx = fmaxf(mx, __shfl_xor(mx, 1));
                mx = fmaxf(mx, __shfl_xor(mx, 2));
                mx = fmaxf(mx, __shfl_xor(mx, 4));
                mx = fmaxf(mx, __shfl_xor(mx, 8));
                const float mnew = fmaxf(m_run[r], mx);
                const float corr = exp2f(m_run[r] - mnew);
                l_run[r] *= corr;
                oh[0][r] *= corr;
                oh[1][r] *= corr;
                m_run[r] = mnew;
            }
        }
        #pragma unroll
        for (int r = 0; r < 4; ++r) {
            const float p0 = exp2f(lv[0][r] - m_run[r]);
            const float p1 = exp2f(lv[1][r] - m_run[r]);
            Ps[w][4*g + r][l16]      = (bf16)p0;
            Ps[w][4*g + r][16 + l16] = (bf16)p1;
            l_run[r] += p0 + p1;
        }

        // wave-local Ps writes must land before our own ds_read
        asm volatile("s_waitcnt lgkmcnt(0)" ::: "memory");
        __builtin_amdgcn_sched_barrier(0);

        // PV
        const bf16x8 pf = *(const bf16x8*)&Ps[w][l16][8*g];
        oh[0] = mfma16(pf, vf0, oh[0]);
        oh[1] = mfma16(pf, vf1, oh[1]);

        // stage next X tile into the other buffer; rotate registers
        if (it + 1 < NT) {
            float* dA = &Xps[cur ^ 1][xq*132 + xm*4];
            dA[0] = xnxA; dA[1] = xnyA; dA[2] = xnzA;
            float* dB = &Xps[cur ^ 1][(xq + 8)*132 + xm*4];
            dB[0] = xnxB; dB[1] = xnyB; dB[2] = xnzB;
            kf0 = kn0; kf1 = kn1; vf0 = vn0; vf1 = vn1;
            pk0 = pn0; pk1 = pn1;
        }
        __syncthreads();
    }

    // epilogue: unnormalized partial oh + (m, l) per row/head
    #pragma unroll
    for (int r = 0; r < 4; ++r) {
        float ls = l_run[r];
        ls += __shfl_xor(ls, 1);
        ls += __shfl_xor(ls, 2);
        ls += __shfl_xor(ls, 4);
        ls += __shfl_xor(ls, 8);
        const int n = q0 + 4*g + r;
        #pragma unroll
        for (int dg = 0; dg < 2; ++dg) {
            const int col = h*32 + dg*16 + l16;
            Ohp[(((size_t)z*NB + b)*NN + n)*ND + col] = oh[dg][r];
        }
        if (l16 == 0) {
            const size_t mi = ((((size_t)z*NB + b)*NN + n)*NH + h)*2;
            ml[mi]   = m_run[r];
            ml[mi+1] = ls;
        }
    }
}

// combine ZSPLIT key-quarters: O1 = Vf + (Σ oh_z w_z) / (Σ l_z w_z)
__global__ __launch_bounds__(256)
void comb_k(const float* __restrict__ Ohp, const float* __restrict__ ml,
            const float* __restrict__ Vf, float* __restrict__ O1)
{
    const int idx = blockIdx.x * 256 + threadIdx.x;
    const int dq = idx & 63;
    const int bn = idx >> 6;
    const int d0 = dq * 4;
    const int h  = dq >> 3;

    const size_t base = ((size_t)bn*NH + h)*2;
    const size_t zstr = (size_t)NB*NN*NH*2;
    float mz[ZSPLIT], lz[ZSPLIT];
    float M = -INFINITY;
    #pragma unroll
    for (int zi = 0; zi < ZSPLIT; ++zi) {
        mz[zi] = ml[base + zi*zstr];
        lz[zi] = ml[base + zi*zstr + 1];
        M = fmaxf(M, mz[zi]);
    }
    float wz[ZSPLIT], den = 0.f;
    #pragma unroll
    for (int zi = 0; zi < ZSPLIT; ++zi) {
        wz[zi] = exp2f(mz[zi] - M);
        den = fmaf(lz[zi], wz[zi], den);
    }
    const float inv = 1.f / den;

    const size_t e = (size_t)bn*ND + d0;
    f32x4 num = {0.f,0.f,0.f,0.f};
    #pragma unroll
    for (int zi = 0; zi < ZSPLIT; ++zi) {
        const f32x4 o = *(const f32x4*)&Ohp[e + (size_t)zi*NB*NN*ND];
        #pragma unroll
        for (int r = 0; r < 4; ++r) num[r] = fmaf(o[r], wz[zi], num[r]);
    }
    const f32x4 vf = *(const f32x4*)&Vf[e];
    f32x4 out;
    #pragma unroll
    for (int r = 0; r < 4; ++r) out[r] = vf[r] + num[r]*inv;
    *(f32x4*)&O1[e] = out;
}

extern "C" void kernel_launch(void* const* d_in, const int* in_sizes, int n_in,
                              void* d_out, int out_size, void* d_ws, size_t ws_size,
                              hipStream_t stream)
{
    const float* Y   = (const float*)d_in[1];
    const float* Xp  = (const float*)d_in[2];
    const float* prq = (const float*)d_in[3];
    const float* prk = (const float*)d_in[4];
    const float* Wq  = (const float*)d_in[5];
    const float* bq  = (const float*)d_in[6];
    const float* Wk  = (const float*)d_in[7];
    const float* bk  = (const float*)d_in[8];
    const float* Wv  = (const float*)d_in[9];
    const float* bv  = (const float*)d_in[10];
    const float* Wo  = (const float*)d_in[11];
    const float* bo  = (const float*)d_in[12];
    const float* Wg1 = (const float*)d_in[13];
    const float* bg1 = (const float*)d_in[14];
    const float* wg2 = (const float*)d_in[15];
    const float* bg2 = (const float*)d_in[16];
    float* out = (float*)d_out;

    const size_t BND = (size_t)NB * NN * ND;   // 1M
    float* Vf  = (float*)d_ws;                           // 4 MB
    float* Ohp = Vf + BND;                               // 16 MB (z=0..3)
    float* ml  = Ohp + (size_t)ZSPLIT*BND;               // 1 MB
    bf16*  Qb  = (bf16*)(ml + (size_t)ZSPLIT*NB*NN*NH*2);// 2 MB
    bf16*  Kb  = Qb + BND;                               // 2 MB
    bf16*  Vt  = Kb + BND;                               // 2 MB
    float* O1  = (float*)Qb;                             // aliases Qb+Kb (dead after attn)

    gemm_k<0><<<dim3(64, 4, 3), 256, 0, stream>>>(
        Y, Wq, bq, Wk, bk, Wv, bv,
        Vf, Qb, Kb, Vt, nullptr, nullptr);

    attn_k<<<dim3(NN/16, NB*2, ZSPLIT), 256, 0, stream>>>(
        Qb, Kb, Vt, Xp, prq, prk, Wg1, bg1, wg2, bg2, Ohp, ml);

    comb_k<<<dim3(1024), 256, 0, stream>>>(Ohp, ml, Vf, O1);

    gemm_k<1><<<dim3(64, 4, 1), 256, 0, stream>>>(
        O1, Wo, bo, Wo, bo, Wo, bo,
        nullptr, nullptr, nullptr, nullptr, out, O1);
}